// Round 20
// baseline (169.466 us; speedup 1.0000x reference)
//
#include <hip/hip_runtime.h>
#include <hip/hip_bf16.h>

typedef __bf16 bf16_t;
typedef bf16_t bf16x4 __attribute__((ext_vector_type(4)));
typedef bf16_t bf16x8 __attribute__((ext_vector_type(8)));
typedef float f32x4 __attribute__((ext_vector_type(4)));

#define AS1 __attribute__((address_space(1)))
#define AS3 __attribute__((address_space(3)))

__device__ __forceinline__ void gload_lds16(const void* g, void* l) {
    __builtin_amdgcn_global_load_lds((const AS1 void*)g, (AS3 void*)l, 16, 0, 0);
}
__device__ __forceinline__ void gload_lds4(const void* g, void* l) {
    __builtin_amdgcn_global_load_lds((const AS1 void*)g, (AS3 void*)l, 4, 0, 0);
}

__device__ __forceinline__ float sigmoidf_(float v) {
    return 1.0f / (1.0f + __expf(-v));
}

// ---------------- fused f32 -> bf16 convert, KB32 blocked output ----------------
__global__ __launch_bounds__(256) void k_convert3(const float* __restrict__ x,
                                                  const float* __restrict__ pr,
                                                  const float* __restrict__ ft,
                                                  bf16_t* __restrict__ XPs,
                                                  bf16_t* __restrict__ F16s) {
    const int n4 = 7168 * 256;
    int i = blockIdx.x * 256 + threadIdx.x;
    const int stride = gridDim.x * 256;
    for (; i < n4; i += stride) {
        float4 v;
        long r;
        int c4;
        bf16_t* dst;
        long R;
        if (i < 1048576) {
            v = ((const float4*)x)[i];
            r = i >> 8; c4 = i & 255; dst = XPs; R = 5120;
        } else if (i < 1310720) {
            const int j = i - 1048576;
            v = ((const float4*)pr)[j];
            r = 4096 + (j >> 8); c4 = j & 255; dst = XPs; R = 5120;
        } else {
            const int j = i - 1310720;
            v = ((const float4*)ft)[j];
            r = j >> 8; c4 = j & 255; dst = F16s; R = 2048;
        }
        const int col = c4 << 2;
        const int kb = col >> 5;
        const int cw = col & 31;
        bf16x4 o;
        o[0] = (bf16_t)v.x; o[1] = (bf16_t)v.y; o[2] = (bf16_t)v.z; o[3] = (bf16_t)v.w;
        *(bf16x4*)(dst + ((long)kb * R + r) * 32 + cw) = o;
    }
}

// ================= GEMM2: ring-4 FP8 + FUSED last-block reduce ===================
// K-loop identical to R19. Epilogue: every block writes its bf16 partial, then
// write -> threadfence -> atomicAdd(cnt[tile]); the 4th (last) block re-reads the
// other 3 z-slabs, adds its own (bf16-rounded, so bit-identical to stored), folds
// rsPart row/col sums, and writes the final f32 output. Deterministic: fixed
// z-order 0..3 summation with all contributions bf16-rounded.
__global__ __launch_bounds__(512, 2) void gemm2_8p(
    const char* __restrict__ A8, const char* __restrict__ B8,
    bf16_t* __restrict__ O1, long zstride,
    const float* __restrict__ rsPart, const float* __restrict__ pa,
    float* __restrict__ out, int* __restrict__ cnt) {
    __shared__ char lds[65536];  // A: 4 x 8KB @0, B: 4 x 8KB @32768
    const int tid = threadIdx.x;
    const int wave = tid >> 6, lane = tid & 63;
    const int wm = wave >> 2, wn = wave & 3;
    const int lm = lane & 15;

    const int gx = gridDim.x, gy = gridDim.y;
    const int o = blockIdx.x + gx * (blockIdx.y + gy * blockIdx.z);
    const int cpx = (gx * gy * (int)gridDim.z) >> 3;
    const int v = (o & 7) * cpx + (o >> 3);
    const int bx = v % gx;
    const int rem = v / gx;
    const int by = rem % gy;
    const int bz = rem / gy;

    const long bm = (long)bx * 256, bn = (long)by * 256;
    const int kb32_0 = bz * 32;

    const int base_a = (lane >> 4) * 2048 + (wm * 128 + lm) * 8;
    const int base_b = (lane >> 4) * 2048 + (wn * 64 + lm) * 8;

    f32x4 acc[8][4] = {};

#define VM4 asm volatile("s_waitcnt vmcnt(4)" ::: "memory")
#define VM2 asm volatile("s_waitcnt vmcnt(2)" ::: "memory")
#define VM0 asm volatile("s_waitcnt vmcnt(0)" ::: "memory")

    auto PFETCH = [&](int pf) {
        const long kb = kb32_0 + pf;
        const int ps = pf & 3;
        const int kg = tid >> 7;
        const int li = (tid & 127) << 4;
        gload_lds16(A8 + kb * 131072 + (long)kg * 32768 + bm * 8 + li,
                    lds + ps * 8192 + wave * 1024);
        gload_lds16(B8 + kb * 32768 + (long)kg * 8192 + bn * 8 + li,
                    lds + 32768 + ps * 8192 + wave * 1024);
    };

#define PHASE2(p, WAITSTMT, DOPF)                                               \
    do {                                                                        \
        WAITSTMT;                                                               \
        __builtin_amdgcn_s_barrier();                                           \
        __builtin_amdgcn_s_setprio(1);                                          \
        const int slot = (p) & 3;                                               \
        const char* sA = lds + slot * 8192;                                     \
        const char* sB = lds + 32768 + slot * 8192;                             \
        long long af[8];                                                        \
        long long bfr[4];                                                       \
        _Pragma("unroll") for (int f = 0; f < 8; ++f)                           \
            af[f] = *(const long long*)(sA + base_a + f * 128);                 \
        _Pragma("unroll") for (int g = 0; g < 4; ++g)                           \
            bfr[g] = *(const long long*)(sB + base_b + g * 128);                \
        if (DOPF) PFETCH((p) + 3);                                              \
        _Pragma("unroll") for (int f = 0; f < 8; ++f)                           \
            _Pragma("unroll") for (int g = 0; g < 4; ++g)                       \
                acc[f][g] = __builtin_amdgcn_mfma_f32_16x16x32_fp8_fp8(         \
                    af[f], bfr[g], acc[f][g], 0, 0, 0);                         \
        __builtin_amdgcn_s_setprio(0);                                          \
    } while (0)

    const int NP = 32;
    PFETCH(0);
    PFETCH(1);
    PFETCH(2);

    for (int p = 0; p < NP - 3; ++p) PHASE2(p, VM4, 1);
    PHASE2(NP - 3, VM4, 0);
    PHASE2(NP - 2, VM2, 0);
    PHASE2(NP - 1, VM0, 0);

#undef PHASE2
#undef VM4
#undef VM2
#undef VM0

    // write own bf16 partial (scrambled-coalesced layout, unchanged)
    const int tile = bx * 4 + by;
    bf16_t* Op = O1 + (long)bz * zstride + (long)tile * 65536 + wave * 8192 + lane * 8;
#pragma unroll
    for (int fg = 0; fg < 8; ++fg)
#pragma unroll
        for (int gp = 0; gp < 2; ++gp) {
            bf16x8 w;
#pragma unroll
            for (int gh = 0; gh < 2; ++gh)
#pragma unroll
                for (int q = 0; q < 4; ++q)
                    w[gh * 4 + q] = (bf16_t)acc[fg][gp * 2 + gh][q];
            *(bf16x8*)(Op + (fg * 2 + gp) * 512) = w;
        }

    // last-block election (write -> release fence -> device-scope atomic)
    __threadfence();
    __shared__ int lastFlag;
    if (tid == 0) lastFlag = (atomicAdd(&cnt[tile], 1) == 3);
    __syncthreads();
    if (!lastFlag) return;
    __threadfence();  // acquire: make other blocks' partial writes visible

    // fold row/col sums into LDS (K-loop LDS free after syncthreads above)
    float* rowsum = (float*)lds;        // [256]
    float* colsum = rowsum + 256;       // [256]
    if (tid < 256) {
        float s = 0.f;
#pragma unroll
        for (int b = 0; b < 8; ++b) s += rsPart[b * 5120 + bm + tid];
        rowsum[tid] = pa[0] * s;
    } else {
        const int cc = tid - 256;
        float s = 0.f;
#pragma unroll
        for (int b = 0; b < 8; ++b) s += rsPart[b * 5120 + 4096 + bn + cc];
        colsum[cc] = s;
    }
    __syncthreads();

    // reduce 4 z-contributions (fixed z order; own z from registers, bf16-rounded)
    const bf16_t* Pbase = O1 + (long)tile * 65536 + wave * 8192 + lane * 8;
    const int er = (lane >> 4) << 2;
    const int ec = lane & 15;
#pragma unroll
    for (int fg = 0; fg < 8; ++fg)
#pragma unroll
        for (int gp = 0; gp < 2; ++gp) {
            float sum[8] = {};
            const long coff = (fg * 2 + gp) * 512;
            for (int z = 0; z < 4; ++z) {
                if (z == bz) {
#pragma unroll
                    for (int gh = 0; gh < 2; ++gh)
#pragma unroll
                        for (int q = 0; q < 4; ++q)
                            sum[gh * 4 + q] += (float)(bf16_t)acc[fg][gp * 2 + gh][q];
                } else {
                    bf16x8 vv = *(const bf16x8*)(Pbase + (long)z * zstride + coff);
#pragma unroll
                    for (int j = 0; j < 8; ++j) sum[j] += (float)vv[j];
                }
            }
#pragma unroll
            for (int gh = 0; gh < 2; ++gh) {
                const int lc = wn * 64 + (gp * 2 + gh) * 16 + ec;
                const float cs = colsum[lc];
#pragma unroll
                for (int q = 0; q < 4; ++q) {
                    const int lr = wm * 128 + fg * 16 + er + q;
                    out[(bm + lr) * 1024 + bn + lc] = sum[gh * 4 + q] - rowsum[lr] - cs;
                }
            }
        }
}

// ================= GEMM1: ring-4 160x256, bf16 in, FP8 KB-grouped out ===========
__global__ __launch_bounds__(512, 2) void gemm1_160(
    const bf16_t* __restrict__ XPs, const bf16_t* __restrict__ F16s,
    char* __restrict__ A8, char* __restrict__ B8,
    float* __restrict__ rsPart,
    const float* __restrict__ pa, const float* __restrict__ pb,
    const float* __restrict__ pt) {
    __shared__ char lds[106496];
    const int tid = threadIdx.x;
    const int wave = tid >> 6, lane = tid & 63;
    const int wm = wave >> 2, wn = wave & 3;

    const int gx = gridDim.x, gy = gridDim.y;
    const int o = blockIdx.x + gx * blockIdx.y;
    const int cpx = (gx * gy) >> 3;
    const int v = (o & 7) * cpx + (o >> 3);
    const int bx = v % gx;
    const int by = v / gx;

    const long bm = (long)bx * 160, bn = (long)by * 256;
    const char* Ab = (const char*)XPs;
    const char* Bb = (const char*)F16s;

    const int swzcb = ((lane >> 4) << 4) ^ (((lane >> 3) & 1) << 5);
    const int base_a = (wm * 80 + (lane & 15)) * 64 + swzcb;
    const int base_b = (wn * 64 + (lane & 15)) * 64 + swzcb;

    f32x4 acc[5][4] = {};

#define VM8 asm volatile("s_waitcnt vmcnt(8)" ::: "memory")
#define VM4 asm volatile("s_waitcnt vmcnt(4)" ::: "memory")
#define VM0 asm volatile("s_waitcnt vmcnt(0)" ::: "memory")

    auto PFETCH = [&](int pf) {
        const int ps = pf & 3;
        const char* Ag = Ab + ((long)pf * 5120 + bm) * 64;
        const char* Bg = Bb + ((long)pf * 2048 + bn) * 64;
        {
            const int oo = tid << 4;
            const int cb = (oo & 63) ^ (((oo >> 9) & 1) << 5);
            gload_lds16(Ag + (oo & ~63) + cb, lds + ps * 10240 + (oo & ~1023));
        }
        {
            const int oo = 8192 + (tid << 2);
            const int cb = (oo & 63) ^ (((oo >> 9) & 1) << 5);
            gload_lds4(Ag + (oo & ~63) + cb, lds + ps * 10240 + 8192 + wave * 256);
        }
#pragma unroll
        for (int j = 0; j < 2; ++j) {
            const int oo = (j * 512 + tid) << 4;
            const int cb = (oo & 63) ^ (((oo >> 9) & 1) << 5);
            gload_lds16(Bg + (oo & ~63) + cb, lds + 40960 + ps * 16384 + (oo & ~1023));
        }
    };

#define PHASE1(p, WAITSTMT, DOPF)                                               \
    do {                                                                        \
        WAITSTMT;                                                               \
        __builtin_amdgcn_s_barrier();                                           \
        __builtin_amdgcn_s_setprio(1);                                          \
        const int slot = (p) & 3;                                               \
        const char* sA = lds + slot * 10240;                                    \
        const char* sB = lds + 40960 + slot * 16384;                            \
        bf16x8 af[5];                                                           \
        bf16x8 bfr[4];                                                          \
        _Pragma("unroll") for (int f = 0; f < 5; ++f)                           \
            af[f] = *(const bf16x8*)(sA + base_a + f * 1024);                   \
        _Pragma("unroll") for (int g = 0; g < 4; ++g)                           \
            bfr[g] = *(const bf16x8*)(sB + base_b + g * 1024);                  \
        if (DOPF) PFETCH((p) + 3);                                              \
        _Pragma("unroll") for (int f = 0; f < 5; ++f)                           \
            _Pragma("unroll") for (int g = 0; g < 4; ++g)                       \
                acc[f][g] = __builtin_amdgcn_mfma_f32_16x16x32_bf16(            \
                    bfr[g], af[f], acc[f][g], 0, 0, 0);                         \
        __builtin_amdgcn_s_setprio(0);                                          \
    } while (0)

    const int NP = 32;
    PFETCH(0);
    PFETCH(1);
    PFETCH(2);

    for (int p = 0; p < NP - 3; ++p) PHASE1(p, VM8, 1);
    PHASE1(NP - 3, VM8, 0);
    PHASE1(NP - 2, VM4, 0);
    PHASE1(NP - 1, VM0, 0);

#undef PHASE1
#undef VM8
#undef VM4
#undef VM0

    // Epilogue: fp8 KB-grouped stores (unchanged from R19)
    const float va = pa[0], vb = pb[0], vt = pt[0];
    const int lm = lane & 15;
    const int ln4 = (lane >> 4) << 2;
    const int kbbase = (int)(bn >> 5) + wn * 2;
    float rs[5];
#pragma unroll
    for (int f = 0; f < 5; ++f) rs[f] = 0.f;

#pragma unroll
    for (int mf = 0; mf < 5; ++mf) {
        const long grow = bm + wm * 80 + mf * 16 + lm;
        const bool isXf = (grow < 4096);
        const long rowidx = isXf ? grow : (grow - 4096);
        const long rowsz = isXf ? 4096 : 1024;
        char* base = isXf ? A8 : B8;
#pragma unroll
        for (int g = 0; g < 4; ++g) {
            float o0[4], o1[4];
            float rsl = 0.f;
#pragma unroll
            for (int q = 0; q < 4; ++q) {
                const float vv = acc[mf][g][q];
                const float s = sigmoidf_(vv);
                const float prod = vv * s;
                o0[q] = isXf ? prod : (vt * prod + va * s);
                o1[q] = isXf ? s : (vb * prod);
                rsl += isXf ? prod : vb * prod;
            }
            rs[mf] += rsl;
            int u0 = __builtin_amdgcn_cvt_pk_fp8_f32(o0[0], o0[1], 0, false);
            u0 = __builtin_amdgcn_cvt_pk_fp8_f32(o0[2], o0[3], u0, true);
            int u1 = __builtin_amdgcn_cvt_pk_fp8_f32(o1[0], o1[1], 0, false);
            u1 = __builtin_amdgcn_cvt_pk_fp8_f32(o1[2], o1[3], u1, true);
            const long kb = kbbase + (g >> 1);
            const int fbase = (g & 1) * 16 + ln4;
            const int kgrp = fbase >> 3;
            const int sub = fbase & 7;
            *(int*)(base + ((kb * 4 + kgrp) * rowsz + rowidx) * 8 + sub) = u0;
            *(int*)(base + (((kb + 64) * 4 + kgrp) * rowsz + rowidx) * 8 + sub) = u1;
        }
    }

    // rowsums
    __syncthreads();
    float* lds_f = (float*)lds;
#pragma unroll
    for (int f = 0; f < 5; ++f) {
        float t = rs[f];
        t += __shfl_xor(t, 16);
        t += __shfl_xor(t, 32);
        if ((lane >> 4) == 0) lds_f[wn * 160 + wm * 80 + f * 16 + lm] = t;
    }
    __syncthreads();
    if (tid < 160) {
        const float s = lds_f[tid] + lds_f[160 + tid] + lds_f[320 + tid] + lds_f[480 + tid];
        rsPart[(long)by * 5120 + bm + tid] = s;
    }
}

extern "C" void kernel_launch(void* const* d_in, const int* in_sizes, int n_in,
                              void* d_out, int out_size, void* d_ws, size_t ws_size,
                              hipStream_t stream) {
    const float* x = (const float*)d_in[0];       // [4096,1024]
    const float* feats = (const float*)d_in[1];   // [2048,1024]
    const float* protos = (const float*)d_in[2];  // [1024,1024]
    const float* pa = (const float*)d_in[3];
    const float* pb = (const float*)d_in[4];
    const float* pt = (const float*)d_in[5];
    float* out = (float*)d_out;                   // [4096,1024]

    constexpr long Bsz = 4096, D = 1024, F = 2048, P = 1024;

    bf16_t* XPs = (bf16_t*)d_ws;                  // KB32: [32][5120][32] bf16, 10 MB
    bf16_t* F16s = XPs + (Bsz + P) * D;           // KB32: [32][2048][32] bf16, 4 MB
    char* A8 = (char*)(F16s + F * D);             // FP8: [128][4][4096][8], 16 MB
    char* B8 = A8 + 128L * 4 * 4096 * 8;          // FP8: [128][4][1024][8], 4 MB
    float* rsPart = (float*)(B8 + 128L * 4 * 1024 * 8);  // [8][5120] f32
    bf16_t* part = (bf16_t*)(rsPart + 8 * 5120);  // 4 x [4096*1024] bf16 (scrambled)
    int* cnt = (int*)(part + 4L * Bsz * P);       // [64] tile counters

    hipMemsetAsync(cnt, 0, 64 * sizeof(int), stream);

    k_convert3<<<2048, 256, 0, stream>>>(x, protos, feats, XPs, F16s);

    // fused GEMM1: [x;protos] @ feats^T  [5120 x 2048], K=1024, 256 blocks
    gemm1_160<<<dim3(32, 8), 512, 0, stream>>>(XPs, F16s, A8, B8, rsPart, pa, pb, pt);

    // GEMM2 split-K=4, fp8 operands + fused last-block reduce/epilogue
    gemm2_8p<<<dim3(Bsz / 256, P / 256, 4), 512, 0, stream>>>(
        A8, B8, part, (long)Bsz * P, rsPart, pa, out, cnt);
}

// Round 21
// 79.011 us; speedup vs baseline: 2.1448x; 2.1448x over previous
//
#include <hip/hip_runtime.h>
#include <hip/hip_bf16.h>

typedef __bf16 bf16_t;
typedef bf16_t bf16x4 __attribute__((ext_vector_type(4)));
typedef bf16_t bf16x8 __attribute__((ext_vector_type(8)));
typedef float f32x4 __attribute__((ext_vector_type(4)));

#define AS1 __attribute__((address_space(1)))
#define AS3 __attribute__((address_space(3)))

__device__ __forceinline__ void gload_lds16(const void* g, void* l) {
    __builtin_amdgcn_global_load_lds((const AS1 void*)g, (AS3 void*)l, 16, 0, 0);
}
__device__ __forceinline__ void gload_lds4(const void* g, void* l) {
    __builtin_amdgcn_global_load_lds((const AS1 void*)g, (AS3 void*)l, 4, 0, 0);
}

__device__ __forceinline__ float sigmoidf_(float v) {
    return 1.0f / (1.0f + __expf(-v));
}

// ---------------- fused f32 -> bf16 convert, KB32 blocked output ----------------
__global__ __launch_bounds__(256) void k_convert3(const float* __restrict__ x,
                                                  const float* __restrict__ pr,
                                                  const float* __restrict__ ft,
                                                  bf16_t* __restrict__ XPs,
                                                  bf16_t* __restrict__ F16s) {
    const int n4 = 7168 * 256;
    int i = blockIdx.x * 256 + threadIdx.x;
    const int stride = gridDim.x * 256;
    for (; i < n4; i += stride) {
        float4 v;
        long r;
        int c4;
        bf16_t* dst;
        long R;
        if (i < 1048576) {
            v = ((const float4*)x)[i];
            r = i >> 8; c4 = i & 255; dst = XPs; R = 5120;
        } else if (i < 1310720) {
            const int j = i - 1048576;
            v = ((const float4*)pr)[j];
            r = 4096 + (j >> 8); c4 = j & 255; dst = XPs; R = 5120;
        } else {
            const int j = i - 1310720;
            v = ((const float4*)ft)[j];
            r = j >> 8; c4 = j & 255; dst = F16s; R = 2048;
        }
        const int col = c4 << 2;
        const int kb = col >> 5;
        const int cw = col & 31;
        bf16x4 o;
        o[0] = (bf16_t)v.x; o[1] = (bf16_t)v.y; o[2] = (bf16_t)v.z; o[3] = (bf16_t)v.w;
        *(bf16x4*)(dst + ((long)kb * R + r) * 32 + cw) = o;
    }
}

// ---------------- split-K reduce + FUSED rowsum fold + final epilogue ------------
__global__ __launch_bounds__(256) void k_reduce4(const bf16_t* __restrict__ part,
                                                 const float* __restrict__ rsPart,
                                                 const float* __restrict__ pa,
                                                 float* __restrict__ out) {
    const int blk = blockIdx.x;
    const int t = threadIdx.x;
    const int idx = blk * 256 + t;
    const int region = idx >> 13;
    const int widx = idx & 8191;
    const int wv = widx >> 10;
    const int chunk = (widx >> 6) & 15;
    const int ln = widx & 63;
    const int bx = region >> 2, by = region & 3;
    const int wm = wv >> 2, wn = wv & 3;
    const int fg = chunk >> 1, gp = chunk & 1;
    const int er = (ln >> 4) << 2, ec = ln & 15;
    const long off = (long)idx * 8;
    const int c = blk & 31;

    __shared__ float rowsum[32];
    __shared__ float colsum[64];
    const int base_r = bx * 256 + wm * 128 + (c & 3) * 32;
    const int base_c = by * 256 + wn * 64;
    if (t < 32) {
        float s = 0.f;
#pragma unroll
        for (int b = 0; b < 8; ++b) s += rsPart[b * 5120 + base_r + t];
        rowsum[t] = pa[0] * s;
    } else if (t < 96) {
        const int cc = t - 32;
        float s = 0.f;
#pragma unroll
        for (int b = 0; b < 8; ++b) s += rsPart[b * 5120 + 4096 + base_c + cc];
        colsum[cc] = s;
    }

    float sum[8] = {};
#pragma unroll
    for (int s = 0; s < 4; ++s) {
        bf16x8 v = *(const bf16x8*)(part + (long)s * 4194304 + off);
#pragma unroll
        for (int j = 0; j < 8; ++j) sum[j] += (float)v[j];
    }
    __syncthreads();

    const int r0 = bx * 256 + wm * 128 + fg * 16 + er;
    const int c0 = by * 256 + wn * 64 + gp * 32 + ec;
#pragma unroll
    for (int q = 0; q < 4; ++q) {
        const float ra = rowsum[r0 + q - base_r];
#pragma unroll
        for (int gh = 0; gh < 2; ++gh) {
            const int col = c0 + gh * 16;
            out[(long)(r0 + q) * 1024 + col] = sum[gh * 4 + q] - ra - colsum[col - base_c];
        }
    }
}

// ================= GEMM2: ring-4, 256x256, FP8 operands (R19 verified) ==========
__global__ __launch_bounds__(512, 2) void gemm2_8p(
    const char* __restrict__ A8, const char* __restrict__ B8,
    bf16_t* __restrict__ O1, long zstride) {
    __shared__ char lds[65536];  // A: 4 x 8KB @0, B: 4 x 8KB @32768
    const int tid = threadIdx.x;
    const int wave = tid >> 6, lane = tid & 63;
    const int wm = wave >> 2, wn = wave & 3;
    const int lm = lane & 15;

    const int gx = gridDim.x, gy = gridDim.y;
    const int o = blockIdx.x + gx * (blockIdx.y + gy * blockIdx.z);
    const int cpx = (gx * gy * (int)gridDim.z) >> 3;
    const int v = (o & 7) * cpx + (o >> 3);
    const int bx = v % gx;
    const int rem = v / gx;
    const int by = rem % gy;
    const int bz = rem / gy;

    const long bm = (long)bx * 256, bn = (long)by * 256;
    const int kb32_0 = bz * 32;

    const int base_a = (lane >> 4) * 2048 + (wm * 128 + lm) * 8;
    const int base_b = (lane >> 4) * 2048 + (wn * 64 + lm) * 8;

    f32x4 acc[8][4] = {};

#define VM4 asm volatile("s_waitcnt vmcnt(4)" ::: "memory")
#define VM2 asm volatile("s_waitcnt vmcnt(2)" ::: "memory")
#define VM0 asm volatile("s_waitcnt vmcnt(0)" ::: "memory")

    auto PFETCH = [&](int pf) {  // slice kb32_0+pf -> slot pf&3 (2 loads/thread)
        const long kb = kb32_0 + pf;
        const int ps = pf & 3;
        const int kg = tid >> 7;          // wave-uniform (wave>>1)
        const int li = (tid & 127) << 4;  // per-lane within kgrp chunk
        gload_lds16(A8 + kb * 131072 + (long)kg * 32768 + bm * 8 + li,
                    lds + ps * 8192 + wave * 1024);
        gload_lds16(B8 + kb * 32768 + (long)kg * 8192 + bn * 8 + li,
                    lds + 32768 + ps * 8192 + wave * 1024);
    };

#define PHASE2(p, WAITSTMT, DOPF)                                               \
    do {                                                                        \
        WAITSTMT;                                                               \
        __builtin_amdgcn_s_barrier();                                           \
        __builtin_amdgcn_s_setprio(1);                                          \
        const int slot = (p) & 3;                                               \
        const char* sA = lds + slot * 8192;                                     \
        const char* sB = lds + 32768 + slot * 8192;                             \
        long long af[8];                                                        \
        long long bfr[4];                                                       \
        _Pragma("unroll") for (int f = 0; f < 8; ++f)                           \
            af[f] = *(const long long*)(sA + base_a + f * 128);                 \
        _Pragma("unroll") for (int g = 0; g < 4; ++g)                           \
            bfr[g] = *(const long long*)(sB + base_b + g * 128);                \
        if (DOPF) PFETCH((p) + 3);                                              \
        _Pragma("unroll") for (int f = 0; f < 8; ++f)                           \
            _Pragma("unroll") for (int g = 0; g < 4; ++g)                       \
                acc[f][g] = __builtin_amdgcn_mfma_f32_16x16x32_fp8_fp8(         \
                    af[f], bfr[g], acc[f][g], 0, 0, 0);                         \
        __builtin_amdgcn_s_setprio(0);                                          \
    } while (0)

    const int NP = 32;
    PFETCH(0);
    PFETCH(1);
    PFETCH(2);

    for (int p = 0; p < NP - 3; ++p) PHASE2(p, VM4, 1);
    PHASE2(NP - 3, VM4, 0);
    PHASE2(NP - 2, VM2, 0);
    PHASE2(NP - 1, VM0, 0);

#undef PHASE2
#undef VM4
#undef VM2
#undef VM0

    // scrambled-coalesced partial write
    bf16_t* Op = O1 + (long)bz * zstride + (long)(bx * 4 + by) * 65536 +
                 wave * 8192 + lane * 8;
#pragma unroll
    for (int fg = 0; fg < 8; ++fg)
#pragma unroll
        for (int gp = 0; gp < 2; ++gp) {
            bf16x8 w;
#pragma unroll
            for (int gh = 0; gh < 2; ++gh)
#pragma unroll
                for (int q = 0; q < 4; ++q)
                    w[gh * 4 + q] = (bf16_t)acc[fg][gp * 2 + gh][q];
            *(bf16x8*)(Op + (fg * 2 + gp) * 512) = w;
        }
}

// ================= GEMM1: ring-4 160x256, bf16 in, FP8 KB-grouped out ===========
__global__ __launch_bounds__(512, 2) void gemm1_160(
    const bf16_t* __restrict__ XPs, const bf16_t* __restrict__ F16s,
    char* __restrict__ A8, char* __restrict__ B8,
    float* __restrict__ rsPart,
    const float* __restrict__ pa, const float* __restrict__ pb,
    const float* __restrict__ pt) {
    __shared__ char lds[106496];
    const int tid = threadIdx.x;
    const int wave = tid >> 6, lane = tid & 63;
    const int wm = wave >> 2, wn = wave & 3;

    const int gx = gridDim.x, gy = gridDim.y;
    const int o = blockIdx.x + gx * blockIdx.y;
    const int cpx = (gx * gy) >> 3;
    const int v = (o & 7) * cpx + (o >> 3);
    const int bx = v % gx;
    const int by = v / gx;

    const long bm = (long)bx * 160, bn = (long)by * 256;
    const char* Ab = (const char*)XPs;
    const char* Bb = (const char*)F16s;

    const int swzcb = ((lane >> 4) << 4) ^ (((lane >> 3) & 1) << 5);
    const int base_a = (wm * 80 + (lane & 15)) * 64 + swzcb;
    const int base_b = (wn * 64 + (lane & 15)) * 64 + swzcb;

    f32x4 acc[5][4] = {};

#define VM8 asm volatile("s_waitcnt vmcnt(8)" ::: "memory")
#define VM4 asm volatile("s_waitcnt vmcnt(4)" ::: "memory")
#define VM0 asm volatile("s_waitcnt vmcnt(0)" ::: "memory")

    auto PFETCH = [&](int pf) {
        const int ps = pf & 3;
        const char* Ag = Ab + ((long)pf * 5120 + bm) * 64;
        const char* Bg = Bb + ((long)pf * 2048 + bn) * 64;
        {
            const int oo = tid << 4;
            const int cb = (oo & 63) ^ (((oo >> 9) & 1) << 5);
            gload_lds16(Ag + (oo & ~63) + cb, lds + ps * 10240 + (oo & ~1023));
        }
        {
            const int oo = 8192 + (tid << 2);
            const int cb = (oo & 63) ^ (((oo >> 9) & 1) << 5);
            gload_lds4(Ag + (oo & ~63) + cb, lds + ps * 10240 + 8192 + wave * 256);
        }
#pragma unroll
        for (int j = 0; j < 2; ++j) {
            const int oo = (j * 512 + tid) << 4;
            const int cb = (oo & 63) ^ (((oo >> 9) & 1) << 5);
            gload_lds16(Bg + (oo & ~63) + cb, lds + 40960 + ps * 16384 + (oo & ~1023));
        }
    };

#define PHASE1(p, WAITSTMT, DOPF)                                               \
    do {                                                                        \
        WAITSTMT;                                                               \
        __builtin_amdgcn_s_barrier();                                           \
        __builtin_amdgcn_s_setprio(1);                                          \
        const int slot = (p) & 3;                                               \
        const char* sA = lds + slot * 10240;                                    \
        const char* sB = lds + 40960 + slot * 16384;                            \
        bf16x8 af[5];                                                           \
        bf16x8 bfr[4];                                                          \
        _Pragma("unroll") for (int f = 0; f < 5; ++f)                           \
            af[f] = *(const bf16x8*)(sA + base_a + f * 1024);                   \
        _Pragma("unroll") for (int g = 0; g < 4; ++g)                           \
            bfr[g] = *(const bf16x8*)(sB + base_b + g * 1024);                  \
        if (DOPF) PFETCH((p) + 3);                                              \
        _Pragma("unroll") for (int f = 0; f < 5; ++f)                           \
            _Pragma("unroll") for (int g = 0; g < 4; ++g)                       \
                acc[f][g] = __builtin_amdgcn_mfma_f32_16x16x32_bf16(            \
                    bfr[g], af[f], acc[f][g], 0, 0, 0);                         \
        __builtin_amdgcn_s_setprio(0);                                          \
    } while (0)

    const int NP = 32;
    PFETCH(0);
    PFETCH(1);
    PFETCH(2);

    for (int p = 0; p < NP - 3; ++p) PHASE1(p, VM8, 1);
    PHASE1(NP - 3, VM8, 0);
    PHASE1(NP - 2, VM4, 0);
    PHASE1(NP - 1, VM0, 0);

#undef PHASE1
#undef VM8
#undef VM4
#undef VM0

    // Epilogue: fp8 KB-grouped stores
    const float va = pa[0], vb = pb[0], vt = pt[0];
    const int lm = lane & 15;
    const int ln4 = (lane >> 4) << 2;
    const int kbbase = (int)(bn >> 5) + wn * 2;
    float rs[5];
#pragma unroll
    for (int f = 0; f < 5; ++f) rs[f] = 0.f;

#pragma unroll
    for (int mf = 0; mf < 5; ++mf) {
        const long grow = bm + wm * 80 + mf * 16 + lm;
        const bool isXf = (grow < 4096);
        const long rowidx = isXf ? grow : (grow - 4096);
        const long rowsz = isXf ? 4096 : 1024;
        char* base = isXf ? A8 : B8;
#pragma unroll
        for (int g = 0; g < 4; ++g) {
            float o0[4], o1[4];
            float rsl = 0.f;
#pragma unroll
            for (int q = 0; q < 4; ++q) {
                const float vv = acc[mf][g][q];
                const float s = sigmoidf_(vv);
                const float prod = vv * s;
                o0[q] = isXf ? prod : (vt * prod + va * s);
                o1[q] = isXf ? s : (vb * prod);
                rsl += isXf ? prod : vb * prod;
            }
            rs[mf] += rsl;
            int u0 = __builtin_amdgcn_cvt_pk_fp8_f32(o0[0], o0[1], 0, false);
            u0 = __builtin_amdgcn_cvt_pk_fp8_f32(o0[2], o0[3], u0, true);
            int u1 = __builtin_amdgcn_cvt_pk_fp8_f32(o1[0], o1[1], 0, false);
            u1 = __builtin_amdgcn_cvt_pk_fp8_f32(o1[2], o1[3], u1, true);
            const long kb = kbbase + (g >> 1);
            const int fbase = (g & 1) * 16 + ln4;
            const int kgrp = fbase >> 3;
            const int sub = fbase & 7;
            *(int*)(base + ((kb * 4 + kgrp) * rowsz + rowidx) * 8 + sub) = u0;
            *(int*)(base + (((kb + 64) * 4 + kgrp) * rowsz + rowidx) * 8 + sub) = u1;
        }
    }

    // rowsums
    __syncthreads();
    float* lds_f = (float*)lds;
#pragma unroll
    for (int f = 0; f < 5; ++f) {
        float t = rs[f];
        t += __shfl_xor(t, 16);
        t += __shfl_xor(t, 32);
        if ((lane >> 4) == 0) lds_f[wn * 160 + wm * 80 + f * 16 + lm] = t;
    }
    __syncthreads();
    if (tid < 160) {
        const float s = lds_f[tid] + lds_f[160 + tid] + lds_f[320 + tid] + lds_f[480 + tid];
        rsPart[(long)by * 5120 + bm + tid] = s;
    }
}

extern "C" void kernel_launch(void* const* d_in, const int* in_sizes, int n_in,
                              void* d_out, int out_size, void* d_ws, size_t ws_size,
                              hipStream_t stream) {
    const float* x = (const float*)d_in[0];       // [4096,1024]
    const float* feats = (const float*)d_in[1];   // [2048,1024]
    const float* protos = (const float*)d_in[2];  // [1024,1024]
    const float* pa = (const float*)d_in[3];
    const float* pb = (const float*)d_in[4];
    const float* pt = (const float*)d_in[5];
    float* out = (float*)d_out;                   // [4096,1024]

    constexpr long Bsz = 4096, D = 1024, F = 2048, P = 1024;

    bf16_t* XPs = (bf16_t*)d_ws;                  // KB32: [32][5120][32] bf16, 10 MB
    bf16_t* F16s = XPs + (Bsz + P) * D;           // KB32: [32][2048][32] bf16, 4 MB
    char* A8 = (char*)(F16s + F * D);             // FP8: [128][4][4096][8], 16 MB
    char* B8 = A8 + 128L * 4 * 4096 * 8;          // FP8: [128][4][1024][8], 4 MB
    float* rsPart = (float*)(B8 + 128L * 4 * 1024 * 8);  // [8][5120] f32
    bf16_t* part = (bf16_t*)(rsPart + 8 * 5120);  // 4 x [4096*1024] bf16 (scrambled)

    k_convert3<<<2048, 256, 0, stream>>>(x, protos, feats, XPs, F16s);

    // fused GEMM1: [x;protos] @ feats^T  [5120 x 2048], K=1024, 256 blocks
    gemm1_160<<<dim3(32, 8), 512, 0, stream>>>(XPs, F16s, A8, B8, rsPart, pa, pb, pt);

    // GEMM2 split-K=4 over kb slices, fp8 operands (scrambled partial layout)
    gemm2_8p<<<dim3(Bsz / 256, P / 256, 4), 512, 0, stream>>>(
        A8, B8, part, (long)Bsz * P);

    // reduce 4 partials + block-local rsPart fold + epilogue
    k_reduce4<<<2048, 256, 0, stream>>>(part, rsPart, pa, out);
}

// Round 22
// 78.217 us; speedup vs baseline: 2.1666x; 1.0101x over previous
//
#include <hip/hip_runtime.h>
#include <hip/hip_bf16.h>

typedef __bf16 bf16_t;
typedef bf16_t bf16x4 __attribute__((ext_vector_type(4)));
typedef bf16_t bf16x8 __attribute__((ext_vector_type(8)));
typedef float f32x4 __attribute__((ext_vector_type(4)));

#define AS1 __attribute__((address_space(1)))
#define AS3 __attribute__((address_space(3)))

__device__ __forceinline__ void gload_lds16(const void* g, void* l) {
    __builtin_amdgcn_global_load_lds((const AS1 void*)g, (AS3 void*)l, 16, 0, 0);
}
__device__ __forceinline__ void gload_lds4(const void* g, void* l) {
    __builtin_amdgcn_global_load_lds((const AS1 void*)g, (AS3 void*)l, 4, 0, 0);
}

__device__ __forceinline__ float sigmoidf_(float v) {
    return 1.0f / (1.0f + __expf(-v));
}

// ---------------- fused f32 -> bf16 convert, KB32 blocked output ----------------
__global__ __launch_bounds__(256) void k_convert3(const float* __restrict__ x,
                                                  const float* __restrict__ pr,
                                                  const float* __restrict__ ft,
                                                  bf16_t* __restrict__ XPs,
                                                  bf16_t* __restrict__ F16s) {
    const int n4 = 7168 * 256;
    int i = blockIdx.x * 256 + threadIdx.x;
    const int stride = gridDim.x * 256;
    for (; i < n4; i += stride) {
        float4 v;
        long r;
        int c4;
        bf16_t* dst;
        long R;
        if (i < 1048576) {
            v = ((const float4*)x)[i];
            r = i >> 8; c4 = i & 255; dst = XPs; R = 5120;
        } else if (i < 1310720) {
            const int j = i - 1048576;
            v = ((const float4*)pr)[j];
            r = 4096 + (j >> 8); c4 = j & 255; dst = XPs; R = 5120;
        } else {
            const int j = i - 1310720;
            v = ((const float4*)ft)[j];
            r = j >> 8; c4 = j & 255; dst = F16s; R = 2048;
        }
        const int col = c4 << 2;
        const int kb = col >> 5;
        const int cw = col & 31;
        bf16x4 o;
        o[0] = (bf16_t)v.x; o[1] = (bf16_t)v.y; o[2] = (bf16_t)v.z; o[3] = (bf16_t)v.w;
        *(bf16x4*)(dst + ((long)kb * R + r) * 32 + cw) = o;
    }
}

// ---------------- split-K reduce + FUSED rowsum fold + final epilogue ------------
__global__ __launch_bounds__(256) void k_reduce4(const bf16_t* __restrict__ part,
                                                 const float* __restrict__ rsPart,
                                                 const float* __restrict__ pa,
                                                 float* __restrict__ out) {
    const int blk = blockIdx.x;
    const int t = threadIdx.x;
    const int idx = blk * 256 + t;
    const int region = idx >> 13;
    const int widx = idx & 8191;
    const int wv = widx >> 10;
    const int chunk = (widx >> 6) & 15;
    const int ln = widx & 63;
    const int bx = region >> 2, by = region & 3;
    const int wm = wv >> 2, wn = wv & 3;
    const int fg = chunk >> 1, gp = chunk & 1;
    const int er = (ln >> 4) << 2, ec = ln & 15;
    const long off = (long)idx * 8;
    const int c = blk & 31;

    __shared__ float rowsum[32];
    __shared__ float colsum[64];
    const int base_r = bx * 256 + wm * 128 + (c & 3) * 32;
    const int base_c = by * 256 + wn * 64;
    if (t < 32) {
        float s = 0.f;
#pragma unroll
        for (int b = 0; b < 8; ++b) s += rsPart[b * 5120 + base_r + t];
        rowsum[t] = pa[0] * s;
    } else if (t < 96) {
        const int cc = t - 32;
        float s = 0.f;
#pragma unroll
        for (int b = 0; b < 8; ++b) s += rsPart[b * 5120 + 4096 + base_c + cc];
        colsum[cc] = s;
    }

    float sum[8] = {};
#pragma unroll
    for (int s = 0; s < 4; ++s) {
        bf16x8 v = *(const bf16x8*)(part + (long)s * 4194304 + off);
#pragma unroll
        for (int j = 0; j < 8; ++j) sum[j] += (float)v[j];
    }
    __syncthreads();

    const int r0 = bx * 256 + wm * 128 + fg * 16 + er;
    const int c0 = by * 256 + wn * 64 + gp * 32 + ec;
#pragma unroll
    for (int q = 0; q < 4; ++q) {
        const float ra = rowsum[r0 + q - base_r];
#pragma unroll
        for (int gh = 0; gh < 2; ++gh) {
            const int col = c0 + gh * 16;
            out[(long)(r0 + q) * 1024 + col] = sum[gh * 4 + q] - ra - colsum[col - base_c];
        }
    }
}

// ================= GEMM2: ring-4 FP8, 16 double-phases (2 kb/phase) =============
// LDS: A 4x16KB @0 (two 8KB kb sub-slices per slot), B 4x16KB @65536.
// PFETCH(double-slice) = 4 loads/thread -> steady VM8, tail VM8/VM4/VM0.
// WAR: prefetch p+3 writes slot (p-1)%4, whose reads sealed by phase-p barrier.
// Accumulation order identical to R19 (kb ascending) -> bit-identical output.
__global__ __launch_bounds__(512, 2) void gemm2_8p(
    const char* __restrict__ A8, const char* __restrict__ B8,
    bf16_t* __restrict__ O1, long zstride) {
    __shared__ char lds[131072];
    const int tid = threadIdx.x;
    const int wave = tid >> 6, lane = tid & 63;
    const int wm = wave >> 2, wn = wave & 3;
    const int lm = lane & 15;

    const int gx = gridDim.x, gy = gridDim.y;
    const int o = blockIdx.x + gx * (blockIdx.y + gy * blockIdx.z);
    const int cpx = (gx * gy * (int)gridDim.z) >> 3;
    const int v = (o & 7) * cpx + (o >> 3);
    const int bx = v % gx;
    const int rem = v / gx;
    const int by = rem % gy;
    const int bz = rem / gy;

    const long bm = (long)bx * 256, bn = (long)by * 256;
    const int kb32_0 = bz * 32;

    const int base_a = (lane >> 4) * 2048 + (wm * 128 + lm) * 8;
    const int base_b = (lane >> 4) * 2048 + (wn * 64 + lm) * 8;

    f32x4 acc[8][4] = {};

#define VM8 asm volatile("s_waitcnt vmcnt(8)" ::: "memory")
#define VM4 asm volatile("s_waitcnt vmcnt(4)" ::: "memory")
#define VM0 asm volatile("s_waitcnt vmcnt(0)" ::: "memory")

    auto PFETCH = [&](int pf) {  // double-slice pf -> slot pf&3 (4 loads/thread)
        const int ps = pf & 3;
        const int kg = tid >> 7;
        const int li = (tid & 127) << 4;
#pragma unroll
        for (int sub = 0; sub < 2; ++sub) {
            const long kb = kb32_0 + pf * 2 + sub;
            gload_lds16(A8 + kb * 131072 + (long)kg * 32768 + bm * 8 + li,
                        lds + ps * 16384 + sub * 8192 + wave * 1024);
            gload_lds16(B8 + kb * 32768 + (long)kg * 8192 + bn * 8 + li,
                        lds + 65536 + ps * 16384 + sub * 8192 + wave * 1024);
        }
    };

#define PHASE2(p, WAITSTMT, DOPF)                                               \
    do {                                                                        \
        WAITSTMT;                                                               \
        __builtin_amdgcn_s_barrier();                                           \
        __builtin_amdgcn_s_setprio(1);                                          \
        const int slot = (p) & 3;                                               \
        _Pragma("unroll") for (int sub = 0; sub < 2; ++sub) {                   \
            const char* sA = lds + slot * 16384 + sub * 8192;                   \
            const char* sB = lds + 65536 + slot * 16384 + sub * 8192;           \
            long long af[8];                                                    \
            long long bfr[4];                                                   \
            _Pragma("unroll") for (int f = 0; f < 8; ++f)                       \
                af[f] = *(const long long*)(sA + base_a + f * 128);             \
            _Pragma("unroll") for (int g = 0; g < 4; ++g)                       \
                bfr[g] = *(const long long*)(sB + base_b + g * 128);            \
            if (sub == 0 && DOPF) PFETCH((p) + 3);                              \
            _Pragma("unroll") for (int f = 0; f < 8; ++f)                       \
                _Pragma("unroll") for (int g = 0; g < 4; ++g)                   \
                    acc[f][g] = __builtin_amdgcn_mfma_f32_16x16x32_fp8_fp8(     \
                        af[f], bfr[g], acc[f][g], 0, 0, 0);                     \
        }                                                                       \
        __builtin_amdgcn_s_setprio(0);                                          \
    } while (0)

    const int NP = 16;
    PFETCH(0);
    PFETCH(1);
    PFETCH(2);

    for (int p = 0; p < NP - 3; ++p) PHASE2(p, VM8, 1);
    PHASE2(NP - 3, VM8, 0);
    PHASE2(NP - 2, VM4, 0);
    PHASE2(NP - 1, VM0, 0);

#undef PHASE2
#undef VM8
#undef VM4
#undef VM0

    // scrambled-coalesced partial write (unchanged)
    bf16_t* Op = O1 + (long)bz * zstride + (long)(bx * 4 + by) * 65536 +
                 wave * 8192 + lane * 8;
#pragma unroll
    for (int fg = 0; fg < 8; ++fg)
#pragma unroll
        for (int gp = 0; gp < 2; ++gp) {
            bf16x8 w;
#pragma unroll
            for (int gh = 0; gh < 2; ++gh)
#pragma unroll
                for (int q = 0; q < 4; ++q)
                    w[gh * 4 + q] = (bf16_t)acc[fg][gp * 2 + gh][q];
            *(bf16x8*)(Op + (fg * 2 + gp) * 512) = w;
        }
}

// ================= GEMM1: ring-3, 16 double-phases, bf16 in, FP8 out ============
// LDS: A 3x20480 @0 (two 10KB kb sub-slices), B 3x32768 @61440 = 156KB total.
// PFETCH(double-slice) = 8 loads/thread; prologue 2 slices; steady VM8; tail
// VM8/VM0. WAR: prefetch p+2 writes slot (p-1)%3, sealed by phase-p barrier.
__global__ __launch_bounds__(512, 2) void gemm1_160(
    const bf16_t* __restrict__ XPs, const bf16_t* __restrict__ F16s,
    char* __restrict__ A8, char* __restrict__ B8,
    float* __restrict__ rsPart,
    const float* __restrict__ pa, const float* __restrict__ pb,
    const float* __restrict__ pt) {
    __shared__ char lds[159744];
    const int tid = threadIdx.x;
    const int wave = tid >> 6, lane = tid & 63;
    const int wm = wave >> 2, wn = wave & 3;

    const int gx = gridDim.x, gy = gridDim.y;
    const int o = blockIdx.x + gx * blockIdx.y;
    const int cpx = (gx * gy) >> 3;
    const int v = (o & 7) * cpx + (o >> 3);
    const int bx = v % gx;
    const int by = v / gx;

    const long bm = (long)bx * 160, bn = (long)by * 256;
    const char* Ab = (const char*)XPs;
    const char* Bb = (const char*)F16s;

    const int swzcb = ((lane >> 4) << 4) ^ (((lane >> 3) & 1) << 5);
    const int base_a = (wm * 80 + (lane & 15)) * 64 + swzcb;
    const int base_b = (wn * 64 + (lane & 15)) * 64 + swzcb;

    f32x4 acc[5][4] = {};

#define VM8 asm volatile("s_waitcnt vmcnt(8)" ::: "memory")
#define VM0 asm volatile("s_waitcnt vmcnt(0)" ::: "memory")

    auto PFETCH = [&](int pf) {  // double-slice pf -> slot pf%3 (8 loads/thread)
        const int ps = pf % 3;
#pragma unroll
        for (int sub = 0; sub < 2; ++sub) {
            const int kb = pf * 2 + sub;
            const char* Ag = Ab + ((long)kb * 5120 + bm) * 64;
            const char* Bg = Bb + ((long)kb * 2048 + bn) * 64;
            {
                const int oo = tid << 4;
                const int cb = (oo & 63) ^ (((oo >> 9) & 1) << 5);
                gload_lds16(Ag + (oo & ~63) + cb,
                            lds + ps * 20480 + sub * 10240 + (oo & ~1023));
            }
            {
                const int oo = 8192 + (tid << 2);
                const int cb = (oo & 63) ^ (((oo >> 9) & 1) << 5);
                gload_lds4(Ag + (oo & ~63) + cb,
                           lds + ps * 20480 + sub * 10240 + 8192 + wave * 256);
            }
#pragma unroll
            for (int j = 0; j < 2; ++j) {
                const int oo = (j * 512 + tid) << 4;
                const int cb = (oo & 63) ^ (((oo >> 9) & 1) << 5);
                gload_lds16(Bg + (oo & ~63) + cb,
                            lds + 61440 + ps * 32768 + sub * 16384 + (oo & ~1023));
            }
        }
    };

#define PHASE1(p, WAITSTMT, DOPF)                                               \
    do {                                                                        \
        WAITSTMT;                                                               \
        __builtin_amdgcn_s_barrier();                                           \
        __builtin_amdgcn_s_setprio(1);                                          \
        const int slot = (p) % 3;                                               \
        _Pragma("unroll") for (int sub = 0; sub < 2; ++sub) {                   \
            const char* sA = lds + slot * 20480 + sub * 10240;                  \
            const char* sB = lds + 61440 + slot * 32768 + sub * 16384;          \
            bf16x8 af[5];                                                       \
            bf16x8 bfr[4];                                                      \
            _Pragma("unroll") for (int f = 0; f < 5; ++f)                       \
                af[f] = *(const bf16x8*)(sA + base_a + f * 1024);               \
            _Pragma("unroll") for (int g = 0; g < 4; ++g)                       \
                bfr[g] = *(const bf16x8*)(sB + base_b + g * 1024);              \
            if (sub == 0 && DOPF) PFETCH((p) + 2);                              \
            _Pragma("unroll") for (int f = 0; f < 5; ++f)                       \
                _Pragma("unroll") for (int g = 0; g < 4; ++g)                   \
                    acc[f][g] = __builtin_amdgcn_mfma_f32_16x16x32_bf16(        \
                        bfr[g], af[f], acc[f][g], 0, 0, 0);                     \
        }                                                                       \
        __builtin_amdgcn_s_setprio(0);                                          \
    } while (0)

    const int NP = 16;
    PFETCH(0);
    PFETCH(1);

    for (int p = 0; p < NP - 2; ++p) PHASE1(p, VM8, 1);
    PHASE1(NP - 2, VM8, 0);
    PHASE1(NP - 1, VM0, 0);

#undef PHASE1
#undef VM8
#undef VM0

    // Epilogue: fp8 KB-grouped stores (unchanged from R19/R21)
    const float va = pa[0], vb = pb[0], vt = pt[0];
    const int lm = lane & 15;
    const int ln4 = (lane >> 4) << 2;
    const int kbbase = (int)(bn >> 5) + wn * 2;
    float rs[5];
#pragma unroll
    for (int f = 0; f < 5; ++f) rs[f] = 0.f;

#pragma unroll
    for (int mf = 0; mf < 5; ++mf) {
        const long grow = bm + wm * 80 + mf * 16 + lm;
        const bool isXf = (grow < 4096);
        const long rowidx = isXf ? grow : (grow - 4096);
        const long rowsz = isXf ? 4096 : 1024;
        char* base = isXf ? A8 : B8;
#pragma unroll
        for (int g = 0; g < 4; ++g) {
            float o0[4], o1[4];
            float rsl = 0.f;
#pragma unroll
            for (int q = 0; q < 4; ++q) {
                const float vv = acc[mf][g][q];
                const float s = sigmoidf_(vv);
                const float prod = vv * s;
                o0[q] = isXf ? prod : (vt * prod + va * s);
                o1[q] = isXf ? s : (vb * prod);
                rsl += isXf ? prod : vb * prod;
            }
            rs[mf] += rsl;
            int u0 = __builtin_amdgcn_cvt_pk_fp8_f32(o0[0], o0[1], 0, false);
            u0 = __builtin_amdgcn_cvt_pk_fp8_f32(o0[2], o0[3], u0, true);
            int u1 = __builtin_amdgcn_cvt_pk_fp8_f32(o1[0], o1[1], 0, false);
            u1 = __builtin_amdgcn_cvt_pk_fp8_f32(o1[2], o1[3], u1, true);
            const long kb = kbbase + (g >> 1);
            const int fbase = (g & 1) * 16 + ln4;
            const int kgrp = fbase >> 3;
            const int sub = fbase & 7;
            *(int*)(base + ((kb * 4 + kgrp) * rowsz + rowidx) * 8 + sub) = u0;
            *(int*)(base + (((kb + 64) * 4 + kgrp) * rowsz + rowidx) * 8 + sub) = u1;
        }
    }

    // rowsums
    __syncthreads();
    float* lds_f = (float*)lds;
#pragma unroll
    for (int f = 0; f < 5; ++f) {
        float t = rs[f];
        t += __shfl_xor(t, 16);
        t += __shfl_xor(t, 32);
        if ((lane >> 4) == 0) lds_f[wn * 160 + wm * 80 + f * 16 + lm] = t;
    }
    __syncthreads();
    if (tid < 160) {
        const float s = lds_f[tid] + lds_f[160 + tid] + lds_f[320 + tid] + lds_f[480 + tid];
        rsPart[(long)by * 5120 + bm + tid] = s;
    }
}

extern "C" void kernel_launch(void* const* d_in, const int* in_sizes, int n_in,
                              void* d_out, int out_size, void* d_ws, size_t ws_size,
                              hipStream_t stream) {
    const float* x = (const float*)d_in[0];       // [4096,1024]
    const float* feats = (const float*)d_in[1];   // [2048,1024]
    const float* protos = (const float*)d_in[2];  // [1024,1024]
    const float* pa = (const float*)d_in[3];
    const float* pb = (const float*)d_in[4];
    const float* pt = (const float*)d_in[5];
    float* out = (float*)d_out;                   // [4096,1024]

    constexpr long Bsz = 4096, D = 1024, F = 2048, P = 1024;

    bf16_t* XPs = (bf16_t*)d_ws;                  // KB32: [32][5120][32] bf16, 10 MB
    bf16_t* F16s = XPs + (Bsz + P) * D;           // KB32: [32][2048][32] bf16, 4 MB
    char* A8 = (char*)(F16s + F * D);             // FP8: [128][4][4096][8], 16 MB
    char* B8 = A8 + 128L * 4 * 4096 * 8;          // FP8: [128][4][1024][8], 4 MB
    float* rsPart = (float*)(B8 + 128L * 4 * 1024 * 8);  // [8][5120] f32
    bf16_t* part = (bf16_t*)(rsPart + 8 * 5120);  // 4 x [4096*1024] bf16 (scrambled)

    k_convert3<<<2048, 256, 0, stream>>>(x, protos, feats, XPs, F16s);

    // fused GEMM1: [x;protos] @ feats^T  [5120 x 2048], K=1024, 256 blocks
    gemm1_160<<<dim3(32, 8), 512, 0, stream>>>(XPs, F16s, A8, B8, rsPart, pa, pb, pt);

    // GEMM2 split-K=4 over kb slices, fp8 operands (scrambled partial layout)
    gemm2_8p<<<dim3(Bsz / 256, P / 256, 4), 512, 0, stream>>>(
        A8, B8, part, (long)Bsz * P);

    // reduce 4 partials + block-local rsPart fold + epilogue
    k_reduce4<<<2048, 256, 0, stream>>>(part, rsPart, pa, out);
}